// Round 8
// baseline (151.020 us; speedup 1.0000x reference)
//
#include <hip/hip_runtime.h>
#include <hip/hip_fp16.h>

#define EPSF 1e-6f

typedef _Float16 f16x8 __attribute__((ext_vector_type(8)));
typedef float f32x4 __attribute__((ext_vector_type(4)));

#define BK 32                  // K-tile (halves); LDS A row = 64 B (4 x 16B segs)
#define SMEM_BYTES 40960       // 4 x 10240 A staging buffers (fg scratch 37,888 fits inside)
#define BUF_BYTES 10240        // A staging: 160 rows x 64 B

#define AS1 __attribute__((address_space(1)))
#define AS3 __attribute__((address_space(3)))

#define VM_WAIT(N) asm volatile("s_waitcnt vmcnt(" #N ")" ::: "memory")
#define LGKM0()    asm volatile("s_waitcnt lgkmcnt(0)" ::: "memory")

// ---------- wave sum -> scalar (SGPR) : pure DPP + readlane, no DS ops ----------
template <int CTRL>
__device__ __forceinline__ float dpp_add(float x) {
    int y = __builtin_amdgcn_update_dpp(0, __float_as_int(x), CTRL, 0xf, 0xf, true);
    return x + __int_as_float(y);
}

__device__ __forceinline__ float wave_sum_bc(float x) {
    x = dpp_add<0xB1>(x);   // quad_perm xor1
    x = dpp_add<0x4E>(x);   // quad_perm xor2
    x = dpp_add<0x141>(x);  // row_half_mirror (xor4)
    x = dpp_add<0x140>(x);  // row_mirror (xor8) -> 16-group sums
    x = dpp_add<0x142>(x);  // row_bcast15
    x = dpp_add<0x143>(x);  // row_bcast31
    return __int_as_float(__builtin_amdgcn_readlane(__float_as_int(x), 63));
}

// ---------------- Phase 1: prepend cls, +EPS, L2-normalize, store fp16 ----------------
// A: row-major [64 groups][80 rows][1024]; rows 0..36 = img 2g, 37..73 = img 2g+1.
// B: FRAGMENT-MAJOR: Bh[((t*32 + kt)*4 + n)*512 + lane*8], lane = q4*16+fr.
//    -> fused's load_bf is 4 contiguous 1 KB dwordx4 loads per tile.
__global__ __launch_bounds__(256) void norm_kernel(
        const float* __restrict__ img_cls, const float* __restrict__ imgs,
        const float* __restrict__ cap_cls, const float* __restrict__ caps,
        __half* __restrict__ Ah, __half* __restrict__ Bh) {
    __shared__ float red[4];
    const int row = blockIdx.x;
    const int tid = threadIdx.x;

    const float* src = nullptr;
    __half* dsth;
    float eps_add = EPSF;
    if (row < 64 * 80) {
        const int g = row / 80, r = row % 80;
        dsth = Ah + (size_t)row * 1024 + tid * 4;
        int i = -1, rr = 0;
        if (r < 37)      { i = 2 * g;     rr = r; }
        else if (r < 74) { i = 2 * g + 1; rr = r - 37; }
        if (i >= 0) {
            if (rr == 0) { src = img_cls + (size_t)i * 1024; eps_add = 0.0f; }
            else         { src = imgs + ((size_t)i * 36 + (rr - 1)) * 1024; }
        }
    } else {
        const int row2 = row - 64 * 80;
        const int t = row2 >> 6, r = row2 & 63;
        const int n = r >> 4, fr = r & 15;
        const int kt = tid >> 3, q4 = (tid >> 1) & 3, j = (tid & 1) * 4;
        dsth = Bh + ((size_t)(t * 32 + kt) * 4 + n) * 512 + (q4 * 16 + fr) * 8 + j;
        if (r == 0)       { src = cap_cls + (size_t)t * 1024; eps_add = 0.0f; }
        else if (r <= 50) { src = caps + ((size_t)t * 50 + (r - 1)) * 1024; }
    }

    if (src == nullptr) {  // pad row: zeros (uniform across block)
        ushort4 z; z.x = z.y = z.z = z.w = 0;
        *reinterpret_cast<ushort4*>(dsth) = z;
        return;
    }

    float4 v = reinterpret_cast<const float4*>(src)[tid];
    v.x += eps_add; v.y += eps_add; v.z += eps_add; v.w += eps_add;
    float ss = v.x * v.x + v.y * v.y + v.z * v.z + v.w * v.w;
    #pragma unroll
    for (int m = 1; m <= 32; m <<= 1) ss += __shfl_xor(ss, m);
    if ((tid & 63) == 0) red[tid >> 6] = ss;
    __syncthreads();
    const float tot = red[0] + red[1] + red[2] + red[3];
    const float rn = 1.0f / sqrtf(tot);

    ushort4 o;
    o.x = __half_as_ushort(__float2half(v.x * rn));
    o.y = __half_as_ushort(__float2half(v.y * rn));
    o.z = __half_as_ushort(__float2half(v.z * rn));
    o.w = __half_as_ushort(__float2half(v.w * rn));
    *reinterpret_cast<ushort4*>(dsth) = o;
}

// ---------------- Phase 2: fused GEMM + Sinkhorn ----------------
// Block 160x128, 4 waves; wave (wm,wn) computes 80x64.
// A staged in LDS, FOUR buffers, staged THREE tiles ahead (2-tile latency
// cover for the L3-resident A panel); conflict-free XOR swizzle.
// B loaded direct global->VGPR from fragment-major Bh, reg double-buffered
// 2 tiles ahead.  ONE barrier per tile. a = 3 (waves 0,1) / 2 (waves 2,3).
__device__ __forceinline__ void stage_octA(const __half* __restrict__ Ag,
                                           __half* buf, int kb, int o, size_t lofs) {
    const __half* src = Ag + (size_t)o * 16384 + kb + lofs;
    __builtin_amdgcn_global_load_lds((const AS1 void*)src,
                                     (AS3 void*)(buf + o * 512), 16, 0, 0);
}

__device__ __forceinline__ void stage_A(const __half* __restrict__ Ag,
                                        __half* buf, int kb, int wave, size_t lofs) {
    stage_octA(Ag, buf, kb, wave, lofs);
    stage_octA(Ag, buf, kb, wave + 4, lofs);
    if (wave < 2) stage_octA(Ag, buf, kb, wave + 8, lofs);
}

__device__ __forceinline__ void ds_af(const __half* buf, int wm, int fr, int q4,
                                      f16x8 af[5]) {
    const int soff = ((q4 ^ ((fr >> 1) & 3)) * 8);   // swizzled seg, halves
    #pragma unroll
    for (int m = 0; m < 5; ++m) {
        const int R = wm * 80 + m * 16 + fr;
        af[m] = *reinterpret_cast<const f16x8*>(buf + R * BK + soff);
    }
}

__device__ __forceinline__ void load_bf(const __half* __restrict__ Bgw, int kt,
                                        f16x8 bf[4]) {
    const __half* p = Bgw + (size_t)kt * 2048;   // Bgw already has +lane*8
    #pragma unroll
    for (int n = 0; n < 4; ++n)
        bf[n] = *reinterpret_cast<const f16x8*>(p + n * 512);
}

__device__ __forceinline__ void mfma_cluster(f32x4 acc[5][4], const f16x8 af[5],
                                             const f16x8 bf[4]) {
    __builtin_amdgcn_s_setprio(1);
    #pragma unroll
    for (int m = 0; m < 5; ++m)
        #pragma unroll
        for (int n = 0; n < 4; ++n)
            acc[m][n] = __builtin_amdgcn_mfma_f32_16x16x32_f16(af[m], bf[n], acc[m][n], 0, 0, 0);
    __builtin_amdgcn_s_setprio(0);
}

__global__ __launch_bounds__(256, 3) void fused_kernel(
        const __half* __restrict__ Ah, const __half* __restrict__ Bh,
        const int* __restrict__ img_lens, const int* __restrict__ cap_lens,
        float* __restrict__ out) {
    __shared__ __align__(16) char smem[SMEM_BYTES];   // 40,960 B -> 3 blocks/CU
    __half* lds0 = reinterpret_cast<__half*>(smem);
    __half* lds1 = reinterpret_cast<__half*>(smem + BUF_BYTES);
    __half* lds2 = reinterpret_cast<__half*>(smem + 2 * BUF_BYTES);
    __half* lds3 = reinterpret_cast<__half*>(smem + 3 * BUF_BYTES);

    // XCD-chunked mapping: 8 consecutive blocks share bx across 8 by slices.
    const int idx = blockIdx.x;            // 0..2047
    const int xcd = idx & 7;
    const int within = idx >> 3;           // 0..255
    const int bx = within >> 3;            // 0..31  (A double-group)
    const int by = xcd * 8 + (within & 7); // 0..63  (cap pair)

    const int tid = threadIdx.x;
    const int wave = tid >> 6;
    const int lane = tid & 63;
    const int wm = wave >> 1, wn = wave & 1;
    const int fr = lane & 15;
    const int q4 = lane >> 4;

    const __half* Ag = Ah + (size_t)bx * 160 * 1024;
    const __half* Bgw = Bh + (size_t)(2 * by + wn) * 65536 + lane * 8;

    // A staging source: rsub = lane>>2 (row in hexadecet); stored slot (lane&3)
    // holds global seg (lane&3) ^ ((lane>>3)&3).  LDS dest linear.
    const int rsub = lane >> 2;
    const int segsrc = (lane & 3) ^ ((lane >> 3) & 3);
    const size_t lofs = (size_t)rsub * 1024 + (size_t)(segsrc * 8);

    f32x4 acc[5][4];
    #pragma unroll
    for (int m = 0; m < 5; ++m)
        #pragma unroll
        for (int n = 0; n < 4; ++n) {
            f32x4 z = {0.0f, 0.0f, 0.0f, 0.0f};
            acc[m][n] = z;
        }

    f16x8 bfA[4], bfB[4];

    // Prologue.  Queue: [A0·a, B0·4, A1·a, B1·4, A2·a]; wait(4+2a) -> A0,B0 done.
    stage_A(Ag, lds0, 0, wave, lofs);
    load_bf(Bgw, 0, bfA);
    stage_A(Ag, lds1, BK, wave, lofs);
    load_bf(Bgw, 1, bfB);
    stage_A(Ag, lds2, 2 * BK, wave, lofs);
    if (wave < 2) { VM_WAIT(10); } else { VM_WAIT(8); }
    __builtin_amdgcn_s_barrier();

    #define GEMM_TILE(KT, RDBUF, STBUF, CUR)                          \
    {                                                                 \
        f16x8 af[5];                                                  \
        ds_af((RDBUF), wm, fr, q4, af);                               \
        mfma_cluster(acc, af, (CUR));                                 \
        load_bf(Bgw, (KT) + 2, (CUR));                                \
        LGKM0();                                                      \
        stage_A(Ag, (STBUF), ((KT) + 3) * BK, wave, lofs);            \
        if (wave < 2) { VM_WAIT(10); } else { VM_WAIT(8); }           \
        __builtin_amdgcn_s_barrier();                                 \
    }

    #pragma unroll 1
    for (int kt = 0; kt < 28; kt += 4) {
        GEMM_TILE(kt,     lds0, lds3, bfA);
        GEMM_TILE(kt + 1, lds1, lds0, bfB);
        GEMM_TILE(kt + 2, lds2, lds1, bfA);
        GEMM_TILE(kt + 3, lds3, lds2, bfB);
    }
    GEMM_TILE(28, lds0, lds3, bfA);   // last full-steady tile (stages A31, loads B30)
    #undef GEMM_TILE

    // ---- tile 29: no staging; load B31 ----
    {
        f16x8 af[5];
        ds_af(lds1, wm, fr, q4, af);
        mfma_cluster(acc, af, bfB);            // B(29)
        load_bf(Bgw, 31, bfB);
        LGKM0();
        // queue: A30·a, B30·4, A31·a, B31·4 ; need A30,B30 -> leave 4+a
        if (wave < 2) { VM_WAIT(7); } else { VM_WAIT(6); }
        __builtin_amdgcn_s_barrier();
    }
    // ---- tile 30 ----
    {
        f16x8 af[5];
        ds_af(lds2, wm, fr, q4, af);
        mfma_cluster(acc, af, bfA);            // B(30), landed at tile-29 wait
        LGKM0();
        VM_WAIT(4);                            // A31 landed; B31 in flight
        __builtin_amdgcn_s_barrier();
    }
    // ---- tile 31 ----
    {
        f16x8 af[5];
        ds_af(lds3, wm, fr, q4, af);
        VM_WAIT(0);                            // B31 landed
        mfma_cluster(acc, af, bfB);
    }

    __syncthreads();   // staging buffers become per-wave fg scratch

    // ---------------- Sinkhorn: wave-private 37x64 f32 fg scratch, BRANCHLESS ----------------
    // Pass p stores only its 37 valid image rows (predicated).
    // Cols XOR-swizzled: col ^ (((srow>>2)&3)<<4). Writes <=2-way (free),
    // reads conflict-free.
    // Inner loops branch-free so independent DPP reduction chains pipeline,
    // BUT chain concurrency is capped in groups of ~10 rows via
    // sched_barrier(0): at launch_bounds(256,3) the unified reg cap is 170
    // (80 AGPR acc + 84 arch = 164 used); interleaving all 37 chains spilled
    // ~12 regs to scratch (R7: WRITE_SIZE 65KB -> 24.6MB). 10 concurrent
    // chains ≈ full latency cover within ~6 spare regs.
    float* fg = reinterpret_cast<float*>(smem) + wave * (37 * 64);
    const int orow = q4 * 4;

    #pragma unroll
    for (int p = 0; p < 2; ++p) {
        if (p) {  // wave-local WAR: pass-0 fg reads must retire before rewrite
            LGKM0();
        }
        #pragma unroll
        for (int pm = 0; pm < 3; ++pm) {
            #pragma unroll
            for (int q = 0; q < 4; ++q) {
                const int lrow = (p ? 32 : 0) + pm * 16 + orow + q;  // wave-local A row
                const int srow = lrow - (p ? 37 : 0);                // scratch row
                const bool ok = p ? (lrow >= 37 && lrow < 74) : (lrow < 37);
                const int sw = ((srow >> 2) & 3) << 4;
                #pragma unroll
                for (int n = 0; n < 4; ++n)
                    if (ok) fg[srow * 64 + ((n * 16 + fr) ^ sw)] = acc[pm + 2 * p][n][q];
            }
        }

        const int i = 4 * bx + 2 * wm + p;
        const int t = 2 * by + wn;
        const int il = img_lens[i] + 1;        // 2..37
        const int cl = cap_lens[t] + 1;        // 2..51
        const bool vcol = lane < cl;

        #define FGR(r_) fg[(r_) * 64 + (lane ^ ((((r_) >> 2) & 3) << 4))]

        float P[37];
        float ts[4] = {0.f, 0.f, 0.f, 0.f};
        #pragma unroll
        for (int r = 0; r < 37; ++r) {
            const float f = FGR(r);                       // always in-bounds
            const bool act = (r < il) && vcol;
            const float pe = act ? __expf((f - 1.0f) * 10.0f) : 0.0f;  // cndmask kills junk
            P[r] = pe;
            ts[r & 3] += pe;
        }
        float tot = (ts[0] + ts[1]) + (ts[2] + ts[3]);
        tot = wave_sum_bc(tot);
        const float s0 = __builtin_amdgcn_rcpf(tot + EPSF);
        #pragma unroll
        for (int r = 0; r < 37; ++r) P[r] *= s0;

        const float rmarg = 1.0f / (float)il;
        const float cmarg = 1.0f / (float)cl;
        float csave = 0.0f;
        for (int it = 0; it < 3; ++it) {
            // Row-rescale: 4 groups of <=10 independent chains; fence between
            // groups caps live DPP temps (prevents scratch spill at reg cap).
            #pragma unroll
            for (int rg = 0; rg < 4; ++rg) {
                const int r0 = rg * 10;
                const int r1 = (r0 + 10 < 37) ? (r0 + 10) : 37;
                #pragma unroll
                for (int r = r0; r < r1; ++r) {
                    const float u = wave_sum_bc(P[r]);
                    P[r] *= rmarg * __builtin_amdgcn_rcpf(u + EPSF);
                }
                __builtin_amdgcn_sched_barrier(0);
            }
            float vs[4] = {EPSF, 0.f, 0.f, 0.f};
            #pragma unroll
            for (int r = 0; r < 37; ++r) vs[r & 3] += P[r];
            const float v = (vs[0] + vs[1]) + (vs[2] + vs[3]);
            const float cs = vcol ? cmarg * __builtin_amdgcn_rcpf(v) : 0.0f;
            if (it < 2) {
                #pragma unroll
                for (int r = 0; r < 37; ++r) P[r] *= cs;
            } else {
                csave = cs;                               // fold last scale into dot
            }
        }

        float ls[4] = {0.f, 0.f, 0.f, 0.f};
        #pragma unroll
        for (int r = 0; r < 37; ++r) {
            const float f = FGR(r);
            const float fm = (r < il) ? f : 0.0f;         // mask BEFORE multiply
            ls[r & 3] = fmaf(fm, P[r], ls[r & 3]);
        }
        float local = csave * ((ls[0] + ls[1]) + (ls[2] + ls[3]));
        local = wave_sum_bc(local);
        if (lane == 0) out[i * 128 + t] = local;
        #undef FGR
    }
}

extern "C" void kernel_launch(void* const* d_in, const int* in_sizes, int n_in,
                              void* d_out, int out_size, void* d_ws, size_t ws_size,
                              hipStream_t stream) {
    const float* img_cls  = (const float*)d_in[0];
    const float* imgs     = (const float*)d_in[1];
    const float* cap_cls  = (const float*)d_in[2];
    const float* caps     = (const float*)d_in[3];
    const int*   img_lens = (const int*)d_in[4];
    const int*   cap_lens = (const int*)d_in[5];
    float* out = (float*)d_out;

    __half* Ah = (__half*)d_ws;                          // 64*80*1024 halves = 10.5 MB
    __half* Bh = Ah + (size_t)64 * 80 * 1024;            // 128*64*1024 halves = 16.8 MB

    norm_kernel<<<64 * 80 + 128 * 64, 256, 0, stream>>>(img_cls, imgs, cap_cls, caps, Ah, Bh);
    fused_kernel<<<2048, 256, 0, stream>>>(Ah, Bh, img_lens, cap_lens, out);
}

// Round 9
// 147.192 us; speedup vs baseline: 1.0260x; 1.0260x over previous
//
#include <hip/hip_runtime.h>
#include <hip/hip_fp16.h>

#define EPSF 1e-6f

typedef _Float16 f16x8 __attribute__((ext_vector_type(8)));
typedef float f32x4 __attribute__((ext_vector_type(4)));

#define BK 32                  // K-tile (halves); LDS A row = 64 B (4 x 16B segs)
#define SMEM_BYTES 75776       // 8 fg regions x 37x64 f32 (4 x 10240 A staging aliases front)
#define BUF_BYTES 10240        // A staging: 160 rows x 64 B

#define AS1 __attribute__((address_space(1)))
#define AS3 __attribute__((address_space(3)))

#define VM_WAIT(N) asm volatile("s_waitcnt vmcnt(" #N ")" ::: "memory")
#define LGKM0()    asm volatile("s_waitcnt lgkmcnt(0)" ::: "memory")

// ---------- wave sum -> scalar (SGPR) : pure DPP + readlane, no DS ops ----------
template <int CTRL>
__device__ __forceinline__ float dpp_add(float x) {
    int y = __builtin_amdgcn_update_dpp(0, __float_as_int(x), CTRL, 0xf, 0xf, true);
    return x + __int_as_float(y);
}

__device__ __forceinline__ float wave_sum_bc(float x) {
    x = dpp_add<0xB1>(x);   // quad_perm xor1
    x = dpp_add<0x4E>(x);   // quad_perm xor2
    x = dpp_add<0x141>(x);  // row_half_mirror (xor4)
    x = dpp_add<0x140>(x);  // row_mirror (xor8) -> 16-group sums
    x = dpp_add<0x142>(x);  // row_bcast15
    x = dpp_add<0x143>(x);  // row_bcast31
    return __int_as_float(__builtin_amdgcn_readlane(__float_as_int(x), 63));
}

// ---------------- Phase 1: prepend cls, +EPS, L2-normalize, store fp16 ----------------
// A: row-major [64 groups][80 rows][1024]; rows 0..36 = img 2g, 37..73 = img 2g+1.
// B: FRAGMENT-MAJOR: Bh[((t*32 + kt)*4 + n)*512 + lane*8], lane = q4*16+fr.
__global__ __launch_bounds__(256) void norm_kernel(
        const float* __restrict__ img_cls, const float* __restrict__ imgs,
        const float* __restrict__ cap_cls, const float* __restrict__ caps,
        __half* __restrict__ Ah, __half* __restrict__ Bh) {
    __shared__ float red[4];
    const int row = blockIdx.x;
    const int tid = threadIdx.x;

    const float* src = nullptr;
    __half* dsth;
    float eps_add = EPSF;
    if (row < 64 * 80) {
        const int g = row / 80, r = row % 80;
        dsth = Ah + (size_t)row * 1024 + tid * 4;
        int i = -1, rr = 0;
        if (r < 37)      { i = 2 * g;     rr = r; }
        else if (r < 74) { i = 2 * g + 1; rr = r - 37; }
        if (i >= 0) {
            if (rr == 0) { src = img_cls + (size_t)i * 1024; eps_add = 0.0f; }
            else         { src = imgs + ((size_t)i * 36 + (rr - 1)) * 1024; }
        }
    } else {
        const int row2 = row - 64 * 80;
        const int t = row2 >> 6, r = row2 & 63;
        const int n = r >> 4, fr = r & 15;
        const int kt = tid >> 3, q4 = (tid >> 1) & 3, j = (tid & 1) * 4;
        dsth = Bh + ((size_t)(t * 32 + kt) * 4 + n) * 512 + (q4 * 16 + fr) * 8 + j;
        if (r == 0)       { src = cap_cls + (size_t)t * 1024; eps_add = 0.0f; }
        else if (r <= 50) { src = caps + ((size_t)t * 50 + (r - 1)) * 1024; }
    }

    if (src == nullptr) {  // pad row: zeros (uniform across block)
        ushort4 z; z.x = z.y = z.z = z.w = 0;
        *reinterpret_cast<ushort4*>(dsth) = z;
        return;
    }

    float4 v = reinterpret_cast<const float4*>(src)[tid];
    v.x += eps_add; v.y += eps_add; v.z += eps_add; v.w += eps_add;
    float ss = v.x * v.x + v.y * v.y + v.z * v.z + v.w * v.w;
    #pragma unroll
    for (int m = 1; m <= 32; m <<= 1) ss += __shfl_xor(ss, m);
    if ((tid & 63) == 0) red[tid >> 6] = ss;
    __syncthreads();
    const float tot = red[0] + red[1] + red[2] + red[3];
    const float rn = 1.0f / sqrtf(tot);

    ushort4 o;
    o.x = __half_as_ushort(__float2half(v.x * rn));
    o.y = __half_as_ushort(__float2half(v.y * rn));
    o.z = __half_as_ushort(__float2half(v.z * rn));
    o.w = __half_as_ushort(__float2half(v.w * rn));
    *reinterpret_cast<ushort4*>(dsth) = o;
}

// ---------------- Phase 2: fused GEMM + Sinkhorn, 8 waves ----------------
// Block 160x128, 512 threads / 8 waves; wave (wm2 = w>>2, wn2 = w&3)
// computes 80x32 -> acc 5x2 f32x4 = 40 regs.  A staged in LDS, 4 buffers,
// 3 tiles ahead; conflict-free XOR swizzle.  B direct global->VGPR
// (fragment-major), reg double-buffered 2 tiles ahead.  One barrier/tile.
// Per tile, 10 A-octets: waves 0..7 take 1, waves 0,1 take a 2nd -> a=2/1.
// Steady vmcnt leaves [A(kt+2)a, B(kt+2)2, A(kt+3)a] = 2a+2 -> 6 / 4.
__device__ __forceinline__ void stage_octA(const __half* __restrict__ Ag,
                                           __half* buf, int kb, int o, size_t lofs) {
    const __half* src = Ag + (size_t)o * 16384 + kb + lofs;
    __builtin_amdgcn_global_load_lds((const AS1 void*)src,
                                     (AS3 void*)(buf + o * 512), 16, 0, 0);
}

__device__ __forceinline__ void stage_A(const __half* __restrict__ Ag,
                                        __half* buf, int kb, int wave, size_t lofs) {
    stage_octA(Ag, buf, kb, wave, lofs);
    if (wave < 2) stage_octA(Ag, buf, kb, wave + 8, lofs);
}

__device__ __forceinline__ void ds_af(const __half* buf, int wm2, int fr, int q4,
                                      f16x8 af[5]) {
    const int soff = ((q4 ^ ((fr >> 1) & 3)) * 8);   // swizzled seg, halves
    #pragma unroll
    for (int m = 0; m < 5; ++m) {
        const int R = wm2 * 80 + m * 16 + fr;
        af[m] = *reinterpret_cast<const f16x8*>(buf + R * BK + soff);
    }
}

__device__ __forceinline__ void load_bf(const __half* __restrict__ Bgw, int kt,
                                        f16x8 bf[2]) {
    const __half* p = Bgw + (size_t)kt * 2048;   // Bgw has +frag_base+lane*8
    bf[0] = *reinterpret_cast<const f16x8*>(p);
    bf[1] = *reinterpret_cast<const f16x8*>(p + 512);
}

__device__ __forceinline__ void mfma_cluster(f32x4 acc[5][2], const f16x8 af[5],
                                             const f16x8 bf[2]) {
    __builtin_amdgcn_s_setprio(1);
    #pragma unroll
    for (int m = 0; m < 5; ++m)
        #pragma unroll
        for (int n = 0; n < 2; ++n)
            acc[m][n] = __builtin_amdgcn_mfma_f32_16x16x32_f16(af[m], bf[n], acc[m][n], 0, 0, 0);
    __builtin_amdgcn_s_setprio(0);
}

__global__ __launch_bounds__(512, 4) void fused_kernel(
        const __half* __restrict__ Ah, const __half* __restrict__ Bh,
        const int* __restrict__ img_lens, const int* __restrict__ cap_lens,
        float* __restrict__ out) {
    __shared__ __align__(16) char smem[SMEM_BYTES];   // 75,776 B -> 2 blocks/CU
    __half* lds0 = reinterpret_cast<__half*>(smem);
    __half* lds1 = reinterpret_cast<__half*>(smem + BUF_BYTES);
    __half* lds2 = reinterpret_cast<__half*>(smem + 2 * BUF_BYTES);
    __half* lds3 = reinterpret_cast<__half*>(smem + 3 * BUF_BYTES);

    // XCD-chunked mapping: 8 consecutive blocks share bx across 8 by slices.
    const int idx = blockIdx.x;            // 0..2047
    const int xcd = idx & 7;
    const int within = idx >> 3;           // 0..255
    const int bx = within >> 3;            // 0..31  (A double-group)
    const int by = xcd * 8 + (within & 7); // 0..63  (cap pair)

    const int tid = threadIdx.x;
    const int wave = tid >> 6;             // 0..7
    const int lane = tid & 63;
    const int wm2 = wave >> 2;             // M half
    const int wn2 = wave & 3;              // N quarter
    const int fr = lane & 15;
    const int q4 = lane >> 4;

    const __half* Ag = Ah + (size_t)bx * 160 * 1024;
    // wave's cap t = 2by + (wn2>>1); frag base = (wn2&1)*2 frags
    const __half* Bgw = Bh + (size_t)(2 * by + (wn2 >> 1)) * 65536
                           + (size_t)((wn2 & 1) * 2) * 512 + lane * 8;

    // A staging source: rsub = lane>>2 (row in hexadecet); stored slot (lane&3)
    // holds global seg (lane&3) ^ ((lane>>3)&3).  LDS dest linear.
    const int rsub = lane >> 2;
    const int segsrc = (lane & 3) ^ ((lane >> 3) & 3);
    const size_t lofs = (size_t)rsub * 1024 + (size_t)(segsrc * 8);

    f32x4 acc[5][2];
    #pragma unroll
    for (int m = 0; m < 5; ++m)
        #pragma unroll
        for (int n = 0; n < 2; ++n) {
            f32x4 z = {0.0f, 0.0f, 0.0f, 0.0f};
            acc[m][n] = z;
        }

    f16x8 bfA[2], bfB[2];

    // Prologue.  Queue: [A0·a, B0·2, A1·a, B1·2, A2·a]; wait leave 2a+2.
    stage_A(Ag, lds0, 0, wave, lofs);
    load_bf(Bgw, 0, bfA);
    stage_A(Ag, lds1, BK, wave, lofs);
    load_bf(Bgw, 1, bfB);
    stage_A(Ag, lds2, 2 * BK, wave, lofs);
    if (wave < 2) { VM_WAIT(6); } else { VM_WAIT(4); }
    __builtin_amdgcn_s_barrier();

    #define GEMM_TILE(KT, RDBUF, STBUF, CUR)                          \
    {                                                                 \
        f16x8 af[5];                                                  \
        ds_af((RDBUF), wm2, fr, q4, af);                              \
        mfma_cluster(acc, af, (CUR));                                 \
        load_bf(Bgw, (KT) + 2, (CUR));                                \
        LGKM0();                                                      \
        stage_A(Ag, (STBUF), ((KT) + 3) * BK, wave, lofs);            \
        if (wave < 2) { VM_WAIT(6); } else { VM_WAIT(4); }            \
        __builtin_amdgcn_s_barrier();                                 \
    }

    #pragma unroll 1
    for (int kt = 0; kt < 28; kt += 4) {
        GEMM_TILE(kt,     lds0, lds3, bfA);
        GEMM_TILE(kt + 1, lds1, lds0, bfB);
        GEMM_TILE(kt + 2, lds2, lds1, bfA);
        GEMM_TILE(kt + 3, lds3, lds2, bfB);
    }
    GEMM_TILE(28, lds0, lds3, bfA);   // stages A31, loads B30
    #undef GEMM_TILE

    // ---- tile 29: no staging; load B31 ----
    {
        f16x8 af[5];
        ds_af(lds1, wm2, fr, q4, af);
        mfma_cluster(acc, af, bfB);            // B(29)
        load_bf(Bgw, 31, bfB);
        LGKM0();
        // queue: A30·a, B30·2, A31·a, B31·2 ; need A30,B30 -> leave a+2
        if (wave < 2) { VM_WAIT(4); } else { VM_WAIT(3); }
        __builtin_amdgcn_s_barrier();
    }
    // ---- tile 30 ----
    {
        f16x8 af[5];
        ds_af(lds2, wm2, fr, q4, af);
        mfma_cluster(acc, af, bfA);            // B(30)
        LGKM0();
        VM_WAIT(2);                            // A31 landed; B31 in flight
        __builtin_amdgcn_s_barrier();
    }
    // ---- tile 31 ----
    {
        f16x8 af[5];
        ds_af(lds3, wm2, fr, q4, af);
        VM_WAIT(0);                            // B31 landed
        mfma_cluster(acc, af, bfB);
    }

    __syncthreads();   // staging buffers become fg scratch (block-shared)

    // ---------------- fg scatter: 8 regions of 37x64 f32 (9,472 B each) ----------------
    // Region rg = ii*2 + tt covers (img 4bx+ii, cap 2by+tt).  Wave (wm2,wn2)
    // writes rows 0..73 of its M-half (both ii = 2wm2, 2wm2+1) x its 32 cols.
    // Cols XOR-swizzled: col ^ (((sr>>2)&3)<<4) -> Sinkhorn reads conflict-free.
    float* fgall = reinterpret_cast<float*>(smem);
    const int tt = wn2 >> 1;
    {
        #pragma unroll
        for (int m = 0; m < 5; ++m) {
            #pragma unroll
            for (int q = 0; q < 4; ++q) {
                const int Rl = m * 16 + q4 * 4 + q;     // 0..79 within M-half
                const int s = (Rl >= 37) ? 1 : 0;
                const int sr = Rl - 37 * s;             // scratch row
                const bool valid = (Rl < 74);
                const int rg = (wm2 * 2 + s) * 2 + tt;
                const int sw = ((sr >> 2) & 3) << 4;
                #pragma unroll
                for (int n = 0; n < 2; ++n) {
                    const int sc = (wn2 & 1) * 32 + n * 16 + fr;
                    if (valid)
                        fgall[rg * 2368 + sr * 64 + (sc ^ sw)] = acc[m][n][q];
                }
            }
        }
    }
    __syncthreads();   // all 8 regions complete

    // ---------------- Sinkhorn: one task per wave (8-way parallel), BRANCHLESS ----------------
    // acc is dead; launch_bounds(512,4) cap = 128 regs; P[37]+temps fit, no spill.
    {
        float* fg = fgall + wave * 2368;
        const int i = 4 * bx + (wave >> 1);
        const int t = 2 * by + (wave & 1);
        const int il = img_lens[i] + 1;        // 2..37
        const int cl = cap_lens[t] + 1;        // 2..51
        const bool vcol = lane < cl;

        #define FGR(r_) fg[(r_) * 64 + (lane ^ ((((r_) >> 2) & 3) << 4))]

        float P[37];
        float ts[4] = {0.f, 0.f, 0.f, 0.f};
        #pragma unroll
        for (int r = 0; r < 37; ++r) {
            const float f = FGR(r);                       // always in-bounds
            const bool act = (r < il) && vcol;
            const float pe = act ? __expf((f - 1.0f) * 10.0f) : 0.0f;
            P[r] = pe;
            ts[r & 3] += pe;
        }
        float tot = (ts[0] + ts[1]) + (ts[2] + ts[3]);
        tot = wave_sum_bc(tot);
        const float s0 = __builtin_amdgcn_rcpf(tot + EPSF);
        #pragma unroll
        for (int r = 0; r < 37; ++r) P[r] *= s0;

        const float rmarg = 1.0f / (float)il;
        const float cmarg = 1.0f / (float)cl;
        float csave = 0.0f;
        for (int it = 0; it < 3; ++it) {
            #pragma unroll
            for (int r = 0; r < 37; ++r) {                // independent DPP chains
                const float u = wave_sum_bc(P[r]);
                P[r] *= rmarg * __builtin_amdgcn_rcpf(u + EPSF);
            }
            float vs[4] = {EPSF, 0.f, 0.f, 0.f};
            #pragma unroll
            for (int r = 0; r < 37; ++r) vs[r & 3] += P[r];
            const float v = (vs[0] + vs[1]) + (vs[2] + vs[3]);
            const float cs = vcol ? cmarg * __builtin_amdgcn_rcpf(v) : 0.0f;
            if (it < 2) {
                #pragma unroll
                for (int r = 0; r < 37; ++r) P[r] *= cs;
            } else {
                csave = cs;                               // fold last scale into dot
            }
        }

        float ls[4] = {0.f, 0.f, 0.f, 0.f};
        #pragma unroll
        for (int r = 0; r < 37; ++r) {
            const float f = FGR(r);
            const float fm = (r < il) ? f : 0.0f;         // mask BEFORE multiply
            ls[r & 3] = fmaf(fm, P[r], ls[r & 3]);
        }
        float local = csave * ((ls[0] + ls[1]) + (ls[2] + ls[3]));
        local = wave_sum_bc(local);
        if (lane == 0) out[i * 128 + t] = local;
        #undef FGR
    }
}

extern "C" void kernel_launch(void* const* d_in, const int* in_sizes, int n_in,
                              void* d_out, int out_size, void* d_ws, size_t ws_size,
                              hipStream_t stream) {
    const float* img_cls  = (const float*)d_in[0];
    const float* imgs     = (const float*)d_in[1];
    const float* cap_cls  = (const float*)d_in[2];
    const float* caps     = (const float*)d_in[3];
    const int*   img_lens = (const int*)d_in[4];
    const int*   cap_lens = (const int*)d_in[5];
    float* out = (float*)d_out;

    __half* Ah = (__half*)d_ws;                          // 64*80*1024 halves = 10.5 MB
    __half* Bh = Ah + (size_t)64 * 80 * 1024;            // 128*64*1024 halves = 16.8 MB

    norm_kernel<<<64 * 80 + 128 * 64, 256, 0, stream>>>(img_cls, imgs, cap_cls, caps, Ah, Bh);
    fused_kernel<<<2048, 512, 0, stream>>>(Ah, Bh, img_lens, cap_lens, out);
}